// Round 15
// baseline (203.446 us; speedup 1.0000x reference)
//
#include <hip/hip_runtime.h>

typedef __attribute__((ext_vector_type(8))) short short8;
typedef __attribute__((ext_vector_type(4))) short short4v;
typedef __attribute__((ext_vector_type(4))) float f32x4;
typedef __attribute__((ext_vector_type(16))) float f32x16;
typedef __attribute__((ext_vector_type(4))) unsigned int u32x4;
typedef __attribute__((ext_vector_type(2))) unsigned int u32x2;
typedef unsigned int u32;

#define D_MODEL 1024
#define HEADS 16
#define KD 64
#define SEQ 2048
#define BATCH 4
#define NTOK (BATCH*SEQ)    /* 8192 */
#define QKV_N (3*D_MODEL)   /* 3072 */

#define WAIT_VM(n) asm volatile("s_waitcnt vmcnt(" #n ")" ::: "memory")

__device__ inline float bf2f(unsigned short u) {
    unsigned x = ((unsigned)u) << 16;
    return __builtin_bit_cast(float, x);
}
__device__ inline unsigned short f2bf(float f) {
    unsigned u = __builtin_bit_cast(unsigned, f);
    u += 0x7FFFu + ((u >> 16) & 1u);
    return (unsigned short)(u >> 16);
}
__device__ __forceinline__ void gload_lds16(const unsigned short* g, unsigned short* l) {
    __builtin_amdgcn_global_load_lds(
        (const __attribute__((address_space(1))) void*)g,
        (__attribute__((address_space(3))) void*)l, 16, 0, 0);
}
__device__ __forceinline__ u32 cvtpk(float lo, float hi) {
    u32 r; asm("v_cvt_pk_bf16_f32 %0, %1, %2" : "=v"(r) : "v"(lo), "v"(hi)); return r;
}
__device__ __forceinline__ void pl32swap(u32& a, u32& b) {
#if __has_builtin(__builtin_amdgcn_permlane32_swap)
    u32x2 r = __builtin_amdgcn_permlane32_swap(a, b, 0, 0);
    a = r[0]; b = r[1];
#else
    u32 pa = (u32)__shfl_xor((int)a, 32, 64);
    u32 pb = (u32)__shfl_xor((int)b, 32, 64);
    bool hb = (threadIdx.x & 32) != 0;
    u32 na = hb ? pb : a;
    u32 nb = hb ? b : pa;
    a = na; b = nb;
#endif
}
__device__ __forceinline__ float pairmax(float x) {
    u32 a = __builtin_bit_cast(u32, x), b = a;
    pl32swap(a, b);
    return fmaxf(x, fmaxf(__builtin_bit_cast(float, a), __builtin_bit_cast(float, b)));
}
__device__ __forceinline__ float pairsum(float x) {
    u32 a = __builtin_bit_cast(u32, x), b = a;
    pl32swap(a, b);
    return __builtin_bit_cast(float, a) + __builtin_bit_cast(float, b);
}

// ---------------------------------------------------------------------------
// x (f32) -> bf16, elementwise, 8 per thread
// ---------------------------------------------------------------------------
__global__ __launch_bounds__(256) void cvt_kernel(
    const float* __restrict__ x, unsigned short* __restrict__ y)
{
    size_t i = (size_t)blockIdx.x * 256 + threadIdx.x;
    f32x4 a = *reinterpret_cast<const f32x4*>(x + i*8);
    f32x4 b = *reinterpret_cast<const f32x4*>(x + i*8 + 4);
    short8 o;
    #pragma unroll
    for (int j = 0; j < 4; ++j) { o[j] = (short)f2bf(a[j]); o[j+4] = (short)f2bf(b[j]); }
    *reinterpret_cast<short8*>(y + i*8) = o;
}

// ---------------------------------------------------------------------------
// WT[n][k] = bf16(W[k][n]); tile 64x64 via LDS
// ---------------------------------------------------------------------------
__global__ __launch_bounds__(256) void transpose_kernel(
    const float* __restrict__ W, unsigned short* __restrict__ WT, int K, int N)
{
    __shared__ unsigned short T[64][80];
    const int tid = threadIdx.x;
    const int n0 = blockIdx.x * 64, k0 = blockIdx.y * 64;

    int r  = tid >> 2;
    int cq = tid & 3;
    const float* src = W + (size_t)(k0 + r) * N + n0 + cq*16;
    #pragma unroll
    for (int q = 0; q < 4; ++q) {
        f32x4 v = *reinterpret_cast<const f32x4*>(src + q*4);
        #pragma unroll
        for (int j = 0; j < 4; ++j) T[cq*16 + q*4 + j][r] = f2bf(v[j]);
    }
    __syncthreads();
    int c  = tid >> 2;
    int rq = tid & 3;
    short8 o0 = *reinterpret_cast<const short8*>(&T[c][rq*16]);
    short8 o1 = *reinterpret_cast<const short8*>(&T[c][rq*16 + 8]);
    unsigned short* dst = WT + (size_t)(n0 + c) * K + k0 + rq*16;
    *reinterpret_cast<short8*>(dst)     = o0;
    *reinterpret_cast<short8*>(dst + 8) = o1;
}

// ---------------------------------------------------------------------------
// GEMM-256: Y = A[M,K](bf16) @ BT[N,K]^T(bf16) + bias(f32).
// 256x256 tile, BK=64, 8 waves (2m x 4n), wave = 128x64 (8x4 frags).
// Dynamic LDS 128KB: 2 bufs x (A 256x64 + B 256x64) bf16, 8-chunk XOR swz.
// 2-deep tile prefetch, counted vmcnt(8), phase-split compute + setprio.
// FUSE: also write vtg (bf16 V^T) and f32 present k/v slices.
// ---------------------------------------------------------------------------
template<int Y_F32, int FUSE>
__global__ __launch_bounds__(512) void gemm256_kernel(
    const unsigned short* __restrict__ A, const unsigned short* __restrict__ BT,
    const float* __restrict__ bias, void* __restrict__ Yv,
    unsigned short* __restrict__ vtg, float* __restrict__ pres,
    int M, int N, int K)
{
    extern __shared__ unsigned short lds[];
    unsigned short* sA = lds;            // [2][256*64]
    unsigned short* sB = lds + 32768;    // [2][256*64]

    const int tid = threadIdx.x, lane = tid & 63, w = tid >> 6;
    const int l15 = lane & 15, lg = lane >> 4;

    const int nwg = gridDim.x * gridDim.y;
    const int bid = blockIdx.y * gridDim.x + blockIdx.x;
    const int swz = (bid & 7) * (nwg >> 3) + (bid >> 3);
    const int n0 = (swz % gridDim.x) * 256;
    const int m0 = (swz / gridDim.x) * 256;

    const int wm = w >> 2;     // 0..1
    const int wn = w & 3;      // 0..3

    f32x4 acc[8][4];
    #pragma unroll
    for (int m = 0; m < 8; ++m)
        #pragma unroll
        for (int n = 0; n < 4; ++n) acc[m][n] = f32x4{0,0,0,0};

    const int nkt = K >> 6;

    // prologue: stage k-tiles 0 and 1 (8 gld-instr/wave per tile)
    #pragma unroll
    for (int d = 0; d < 2; ++d) {
        const int k = d << 6;
        #pragma unroll
        for (int j = 0; j < 4; ++j) {
            int cidx = j*512 + tid;               // 0..2047
            int row = cidx >> 3, c = cidx & 7;
            int sc = c ^ (row & 7);
            gload_lds16(&A[(size_t)(m0 + row) * K + k + sc*8], &sA[d*16384 + cidx*8]);
        }
        #pragma unroll
        for (int j = 0; j < 4; ++j) {
            int cidx = j*512 + tid;
            int row = cidx >> 3, c = cidx & 7;
            int sc = c ^ (row & 7);
            gload_lds16(&BT[(size_t)(n0 + row) * K + k + sc*8], &sB[d*16384 + cidx*8]);
        }
    }

    for (int kt = 0; kt < nkt; ++kt) {
        const int buf = kt & 1;

        if (kt == nkt - 1) { WAIT_VM(0); } else { WAIT_VM(8); }
        __builtin_amdgcn_sched_barrier(0);
        __builtin_amdgcn_s_barrier();     // tile kt fully visible

        short8 bf[4];
        #pragma unroll
        for (int p = 0; p < 4; ++p) {
            const int ksub = p >> 1, mh = p & 1;
            if (mh == 0) {
                #pragma unroll
                for (int nf = 0; nf < 4; ++nf) {
                    int row = wn*64 + nf*16 + l15;
                    int ch  = (4*ksub + lg) ^ (row & 7);
                    bf[nf] = *reinterpret_cast<const short8*>(
                        &sB[buf*16384 + row*64 + ch*8]);
                }
            }
            short8 af[4];
            #pragma unroll
            for (int i = 0; i < 4; ++i) {
                int row = wm*128 + (mh*4 + i)*16 + l15;
                int ch  = (4*ksub + lg) ^ (row & 7);
                af[i] = *reinterpret_cast<const short8*>(
                    &sA[buf*16384 + row*64 + ch*8]);
            }
            __builtin_amdgcn_s_setprio(1);
            #pragma unroll
            for (int i = 0; i < 4; ++i)
                #pragma unroll
                for (int nf = 0; nf < 4; ++nf)
                    acc[mh*4 + i][nf] = __builtin_amdgcn_mfma_f32_16x16x32_bf16(
                        af[i], bf[nf], acc[mh*4 + i][nf], 0, 0, 0);
            __builtin_amdgcn_s_setprio(0);
        }

        __builtin_amdgcn_s_barrier();     // all waves done reading buf
        __builtin_amdgcn_sched_barrier(0);
        if (kt + 2 < nkt) {               // prefetch tile kt+2 into freed buf
            const int k2 = (kt + 2) << 6;
            #pragma unroll
            for (int j = 0; j < 4; ++j) {
                int cidx = j*512 + tid;
                int row = cidx >> 3, c = cidx & 7;
                int sc = c ^ (row & 7);
                gload_lds16(&A[(size_t)(m0 + row) * K + k2 + sc*8], &sA[buf*16384 + cidx*8]);
            }
            #pragma unroll
            for (int j = 0; j < 4; ++j) {
                int cidx = j*512 + tid;
                int row = cidx >> 3, c = cidx & 7;
                int sc = c ^ (row & 7);
                gload_lds16(&BT[(size_t)(n0 + row) * K + k2 + sc*8], &sB[buf*16384 + cidx*8]);
            }
        }
    }

    #pragma unroll
    for (int nf = 0; nf < 4; ++nf) {
        int col = n0 + wn*64 + nf*16 + l15;
        float bv = bias[col];
        #pragma unroll
        for (int mf = 0; mf < 8; ++mf) {
            int row0 = m0 + wm*128 + mf*16 + lg*4;
            float v0 = acc[mf][nf][0] + bv;
            float v1 = acc[mf][nf][1] + bv;
            float v2 = acc[mf][nf][2] + bv;
            float v3 = acc[mf][nf][3] + bv;
            if (Y_F32) {
                float* Y = (float*)Yv;
                Y[(size_t)(row0+0) * N + col] = v0;
                Y[(size_t)(row0+1) * N + col] = v1;
                Y[(size_t)(row0+2) * N + col] = v2;
                Y[(size_t)(row0+3) * N + col] = v3;
            } else {
                unsigned short* Y = (unsigned short*)Yv;
                Y[(size_t)(row0+0) * N + col] = f2bf(v0);
                Y[(size_t)(row0+1) * N + col] = f2bf(v1);
                Y[(size_t)(row0+2) * N + col] = f2bf(v2);
                Y[(size_t)(row0+3) * N + col] = f2bf(v3);
            }
            if (FUSE && n0 < D_MODEL) {   // V cols: vtg (bf16 V^T) + f32 present[1]
                int hh = col >> 6, dd = col & 63;
                int bb = row0 >> 11, ss = row0 & (SEQ - 1);
                short4v pk;
                pk[0] = (short)f2bf(v0); pk[1] = (short)f2bf(v1);
                pk[2] = (short)f2bf(v2); pk[3] = (short)f2bf(v3);
                *reinterpret_cast<short4v*>(
                    vtg + (((size_t)bb*HEADS + hh)*KD + dd)*SEQ + ss) = pk;
                float* pv = pres + (size_t)BATCH*HEADS*SEQ*KD
                          + (((size_t)bb*HEADS + hh)*SEQ + ss)*KD + dd;
                pv[0] = v0; pv[KD] = v1; pv[2*KD] = v2; pv[3*KD] = v3;
            }
            if (FUSE && n0 >= 2*D_MODEL) {  // K cols: f32 present[0]
                int rel = col - 2*D_MODEL;
                int hh = rel >> 6, dd = rel & 63;
                int bb = row0 >> 11, ss = row0 & (SEQ - 1);
                float* pk2 = pres + (((size_t)bb*HEADS + hh)*SEQ + ss)*KD + dd;
                pk2[0] = v0; pk2[KD] = v1; pk2[2*KD] = v2; pk2[3*KD] = v3;
            }
        }
    }
}

// ---------------------------------------------------------------------------
// GEMM-128 (r14 proven): used for out = aout @ W_proj + b_proj.
// ---------------------------------------------------------------------------
template<int Y_F32>
__global__ __launch_bounds__(256) void gemm_bt_kernel(
    const unsigned short* __restrict__ A, const unsigned short* __restrict__ BT,
    const float* __restrict__ bias, void* __restrict__ Yv,
    int M, int N, int K)
{
    __shared__ unsigned short sA[2][128*64];
    __shared__ unsigned short sB[2][128*64];

    const int tid = threadIdx.x, lane = tid & 63, w = tid >> 6;
    const int l15 = lane & 15, lg = lane >> 4;

    const int nwg = gridDim.x * gridDim.y;
    const int bid = blockIdx.y * gridDim.x + blockIdx.x;
    const int swz = (bid & 7) * (nwg >> 3) + (bid >> 3);
    const int n0 = (swz % gridDim.x) * 128;
    const int m0 = (swz / gridDim.x) * 128;

    const int wr = w >> 1, wc = w & 1;

    f32x4 acc[4][4];
    #pragma unroll
    for (int m = 0; m < 4; ++m)
        #pragma unroll
        for (int n = 0; n < 4; ++n) acc[m][n] = f32x4{0,0,0,0};

    const int ldrow = (lane >> 3);
    const int slot  = lane & 7;
    const int nkt = K >> 6;

    #pragma unroll
    for (int i = 0; i < 4; ++i) {
        int kb  = w*4 + i;
        int row = kb*8 + ldrow;
        int sc  = slot ^ (row & 7);
        gload_lds16(&A [(size_t)(m0 + row) * K + sc*8], &sA[0][kb*512]);
        gload_lds16(&BT[(size_t)(n0 + row) * K + sc*8], &sB[0][kb*512]);
    }
    #pragma unroll
    for (int i = 0; i < 4; ++i) {
        int kb  = w*4 + i;
        int row = kb*8 + ldrow;
        int sc  = slot ^ (row & 7);
        gload_lds16(&A [(size_t)(m0 + row) * K + 64 + sc*8], &sA[1][kb*512]);
        gload_lds16(&BT[(size_t)(n0 + row) * K + 64 + sc*8], &sB[1][kb*512]);
    }

    for (int kt = 0; kt < nkt; ++kt) {
        const int buf = kt & 1;

        if (kt == nkt - 1) { WAIT_VM(0); } else { WAIT_VM(8); }
        __builtin_amdgcn_sched_barrier(0);
        __builtin_amdgcn_s_barrier();

        #pragma unroll
        for (int kk = 0; kk < 2; ++kk) {
            short8 af[4], bfr[4];
            #pragma unroll
            for (int m = 0; m < 4; ++m) {
                int row = wr*64 + m*16 + l15;
                int ch  = (4*kk + lg) ^ (row & 7);
                af[m] = *reinterpret_cast<const short8*>(&sA[buf][row*64 + ch*8]);
            }
            #pragma unroll
            for (int n = 0; n < 4; ++n) {
                int row = wc*64 + n*16 + l15;
                int ch  = (4*kk + lg) ^ (row & 7);
                bfr[n] = *reinterpret_cast<const short8*>(&sB[buf][row*64 + ch*8]);
            }
            __builtin_amdgcn_s_setprio(1);
            #pragma unroll
            for (int m = 0; m < 4; ++m)
                #pragma unroll
                for (int n = 0; n < 4; ++n)
                    acc[m][n] = __builtin_amdgcn_mfma_f32_16x16x32_bf16(
                        af[m], bfr[n], acc[m][n], 0, 0, 0);
            __builtin_amdgcn_s_setprio(0);
        }

        __builtin_amdgcn_s_barrier();
        __builtin_amdgcn_sched_barrier(0);
        if (kt + 2 < nkt) {
            const int k2 = (kt + 2) << 6;
            #pragma unroll
            for (int i = 0; i < 4; ++i) {
                int kb  = w*4 + i;
                int row = kb*8 + ldrow;
                int sc  = slot ^ (row & 7);
                gload_lds16(&A [(size_t)(m0 + row) * K + k2 + sc*8], &sA[buf][kb*512]);
                gload_lds16(&BT[(size_t)(n0 + row) * K + k2 + sc*8], &sB[buf][kb*512]);
            }
        }
    }

    #pragma unroll
    for (int n = 0; n < 4; ++n) {
        int col = n0 + wc*64 + n*16 + l15;
        float bv = bias[col];
        #pragma unroll
        for (int m = 0; m < 4; ++m) {
            int row0 = m0 + wr*64 + m*16 + lg*4;
            float v0 = acc[m][n][0] + bv;
            float v1 = acc[m][n][1] + bv;
            float v2 = acc[m][n][2] + bv;
            float v3 = acc[m][n][3] + bv;
            if (Y_F32) {
                float* Y = (float*)Yv;
                Y[(size_t)(row0+0) * N + col] = v0;
                Y[(size_t)(row0+1) * N + col] = v1;
                Y[(size_t)(row0+2) * N + col] = v2;
                Y[(size_t)(row0+3) * N + col] = v3;
            } else {
                unsigned short* Y = (unsigned short*)Yv;
                Y[(size_t)(row0+0) * N + col] = f2bf(v0);
                Y[(size_t)(row0+1) * N + col] = f2bf(v1);
                Y[(size_t)(row0+2) * N + col] = f2bf(v2);
                Y[(size_t)(row0+3) * N + col] = f2bf(v3);
            }
        }
    }
}

// ---------------------------------------------------------------------------
// Flash attention (r14 proven): swapped-operand 32x32 MFMA, wave-paired
// q-tiles, shared K/V staging, 2-deep counted-vmcnt pipeline.
// ---------------------------------------------------------------------------
__global__ __launch_bounds__(512) void attn_kernel(
    const unsigned short* __restrict__ qkv,
    const unsigned short* __restrict__ vtg,
    unsigned short* __restrict__ aout)
{
    __shared__ unsigned short Kl[2][64*64];
    __shared__ unsigned short Vl[2][64*64];

    const int tid  = threadIdx.x;
    const int lane = tid & 63;
    const int w    = tid >> 6;
    const int wg   = w >> 2;
    const int wl   = w & 3;
    const int l31  = lane & 31, hi = lane >> 5;

    const int bid = blockIdx.x;
    const int hb  = bid & 63;
    const int i   = 7 - (bid >> 6);
    const int qb  = 2*i + wg;
    const int h = hb & 15, b = hb >> 4;

    const unsigned short* base  = qkv + (size_t)b * SEQ * QKV_N;
    const unsigned short* vbase = vtg + ((size_t)b * HEADS + h) * KD * SEQ;
    const int qoff = D_MODEL + h*KD;
    const int koff = 2*D_MODEL + h*KD;

    const float SCALE2 = 0.125f * 1.44269504088896f;
    const float THR_RAW = 44.36f;

    const int ldrow = lane >> 3;
    const int slot  = lane & 7;
    const int ksw   = l31 & 7;

    const int q0 = qb * 128;
    const int qrow  = q0 + wl*32 + l31;
    const int qminw = q0 + wl*32;

    short8 qf[4];
    #pragma unroll
    for (int ks = 0; ks < 4; ++ks)
        qf[ks] = *reinterpret_cast<const short8*>(
            base + (size_t)qrow * QKV_N + qoff + ks*16 + hi*8);

    f32x16 o0, o1;
    #pragma unroll
    for (int r = 0; r < 16; ++r) { o0[r] = 0.f; o1[r] = 0.f; }
    float m = -1e30f, msc = -1e30f * 0.180336887f, sr = 0.f;

    const int nt = 4*i + 4;

    {
        int row = w*8 + ldrow, sc = slot ^ (row & 7);
        gload_lds16(&base[(size_t)row * QKV_N + koff + sc*8], &Kl[0][w*512]);
        gload_lds16(&vbase[(size_t)row * SEQ + sc*8],         &Vl[0][w*512]);
        gload_lds16(&base[(size_t)(64 + row) * QKV_N + koff + sc*8], &Kl[1][w*512]);
        gload_lds16(&vbase[(size_t)row * SEQ + 64 + sc*8],           &Vl[1][w*512]);
    }

    for (int t = 0; t < nt; ++t) {
        const int buf = t & 1;

        if (t == nt - 1) { WAIT_VM(0); } else { WAIT_VM(2); }
        __builtin_amdgcn_sched_barrier(0);
        __builtin_amdgcn_s_barrier();

        const int d0 = qminw - t*64;
        if (d0 > -32) {
            f32x16 sa, sb;
            #pragma unroll
            for (int r = 0; r < 16; ++r) { sa[r] = 0.f; sb[r] = 0.f; }
            __builtin_amdgcn_s_setprio(1);
            #pragma unroll
            for (int ks = 0; ks < 4; ++ks) {
                short8 kf = *reinterpret_cast<const short8*>(
                    &Kl[buf][l31*64 + ((2*ks + hi) ^ ksw)*8]);
                sa = __builtin_amdgcn_mfma_f32_32x32x16_bf16(kf, qf[ks], sa, 0, 0, 0);
            }
            #pragma unroll
            for (int ks = 0; ks < 4; ++ks) {
                short8 kf = *reinterpret_cast<const short8*>(
                    &Kl[buf][(32 + l31)*64 + ((2*ks + hi) ^ ksw)*8]);
                sb = __builtin_amdgcn_mfma_f32_32x32x16_bf16(kf, qf[ks], sb, 0, 0, 0);
            }
            __builtin_amdgcn_s_setprio(0);

            if (d0 <= 32) {
                const int kqA = l31 + d0      - 4*hi;
                const int kqB = l31 + d0 - 32 - 4*hi;
                #pragma unroll
                for (int r = 0; r < 16; ++r) {
                    const int cr = (r & 3) + 8*(r >> 2);
                    if (d0 == 0) sa[r] = (cr <= kqA) ? sa[r] : -1e30f;
                    sb[r] = (cr <= kqB) ? sb[r] : -1e30f;
                }
            }

            float x[8];
            #pragma unroll
            for (int ii = 0; ii < 8; ++ii)
                x[ii] = fmaxf(fmaxf(sa[2*ii], sa[2*ii+1]), fmaxf(sb[2*ii], sb[2*ii+1]));
            float pm = fmaxf(fmaxf(fmaxf(x[0], x[1]), fmaxf(x[2], x[3])),
                             fmaxf(fmaxf(x[4], x[5]), fmaxf(x[6], x[7])));
            pm = pairmax(pm);
            if (!__all(pm <= m + THR_RAW)) {
                float mn  = fmaxf(m, pm);
                float fac = exp2f((m - mn) * SCALE2);
                sr *= fac;
                #pragma unroll
                for (int r = 0; r < 16; ++r) { o0[r] *= fac; o1[r] *= fac; }
                m = mn; msc = m * SCALE2;
            }

            #pragma unroll
            for (int r = 0; r < 16; ++r) {
                sa[r] = exp2f(sa[r]*SCALE2 - msc);
                sb[r] = exp2f(sb[r]*SCALE2 - msc);
            }
            float u[8];
            #pragma unroll
            for (int ii = 0; ii < 8; ++ii)
                u[ii] = (sa[2*ii] + sa[2*ii+1]) + (sb[2*ii] + sb[2*ii+1]);
            float ts = ((u[0]+u[1]) + (u[2]+u[3])) + ((u[4]+u[5]) + (u[6]+u[7]));
            sr += pairsum(ts);

            u32 WA[8], WB[8];
            #pragma unroll
            for (int wi = 0; wi < 8; ++wi) {
                WA[wi] = cvtpk(sa[2*wi], sa[2*wi+1]);
                WB[wi] = cvtpk(sb[2*wi], sb[2*wi+1]);
            }

            #pragma unroll
            for (int h32 = 0; h32 < 2; ++h32) {
                #pragma unroll
                for (int ks = 0; ks < 2; ++ks) {
                    u32 W0 = h32 ? WB[4*ks+0] : WA[4*ks+0];
                    u32 W1 = h32 ? WB[4*ks+1] : WA[4*ks+1];
                    u32 W2 = h32 ? WB[4*ks+2] : WA[4*ks+2];
                    u32 W3 = h32 ? WB[4*ks+3] : WA[4*ks+3];
                    u32 s0 = hi ? W0 : W2;
                    u32 s1 = hi ? W1 : W3;
                    u32 r0 = (u32)__shfl_xor((int)s0, 32, 64);
                    u32 r1 = (u32)__shfl_xor((int)s1, 32, 64);
                    u32x4 wv;
                    wv[0] = hi ? r0 : W0;
                    wv[1] = hi ? r1 : W1;
                    wv[2] = hi ? W2 : r0;
                    wv[3] = hi ? W3 : r1;
                    short8 pfrag = __builtin_bit_cast(short8, wv);
                    __builtin_amdgcn_s_setprio(1);
                    #pragma unroll
                    for (int dt = 0; dt < 2; ++dt) {
                        short8 vf = *reinterpret_cast<const short8*>(
                            &Vl[buf][(dt*32 + l31)*64 + ((4*h32 + 2*ks + hi) ^ ksw)*8]);
                        if (dt == 0)
                            o0 = __builtin_amdgcn_mfma_f32_32x32x16_bf16(vf, pfrag, o0, 0, 0, 0);
                        else
                            o1 = __builtin_amdgcn_mfma_f32_32x32x16_bf16(vf, pfrag, o1, 0, 0, 0);
                    }
                    __builtin_amdgcn_s_setprio(0);
                }
            }
        }

        __builtin_amdgcn_s_barrier();
        __builtin_amdgcn_sched_barrier(0);
        if (t + 2 < nt) {
            int row = w*8 + ldrow, sc = slot ^ (row & 7);
            gload_lds16(&base[(size_t)((t+2)*64 + row) * QKV_N + koff + sc*8],
                        &Kl[buf][w*512]);
            gload_lds16(&vbase[(size_t)row * SEQ + (t+2)*64 + sc*8],
                        &Vl[buf][w*512]);
        }
    }

    const float inv = 1.0f / sr;
    unsigned short* orow = aout + ((size_t)b * SEQ + qrow) * D_MODEL + h*KD;
    #pragma unroll
    for (int dt = 0; dt < 2; ++dt) {
        #pragma unroll
        for (int g = 0; g < 4; ++g) {
            short4v pk;
            #pragma unroll
            for (int j = 0; j < 4; ++j) {
                float v = (dt == 0 ? o0[4*g + j] : o1[4*g + j]) * inv;
                pk[j] = (short)f2bf(v);
            }
            *reinterpret_cast<short4v*>(orow + dt*32 + 8*g + 4*hi) = pk;
        }
    }
}

// ---------------------------------------------------------------------------
extern "C" void kernel_launch(void* const* d_in, const int* in_sizes, int n_in,
                              void* d_out, int out_size, void* d_ws, size_t ws_size,
                              hipStream_t stream)
{
    const float* x      = (const float*)d_in[0];
    const float* W_attn = (const float*)d_in[1];
    const float* b_attn = (const float*)d_in[2];
    const float* W_proj = (const float*)d_in[3];
    const float* b_proj = (const float*)d_in[4];
    float* out = (float*)d_out;

    unsigned short* qkv  = (unsigned short*)d_ws;                  // [8192][3072]
    unsigned short* xbf  = qkv + (size_t)NTOK * QKV_N;             // [8192][1024] (= aout later)
    unsigned short* aout = xbf;
    unsigned short* WT   = xbf + (size_t)NTOK * D_MODEL;           // [3072][1024]
    unsigned short* WpT  = WT + (size_t)QKV_N * D_MODEL;           // [1024][1024]
    unsigned short* vtg  = WpT + (size_t)D_MODEL * D_MODEL;        // [4][16][64][2048]
    float* pres = out + (size_t)NTOK * D_MODEL;                    // [2,4,16,2048,64] f32

    // opt-in to 128KB dynamic LDS for the 256^2 GEMM (idempotent)
    (void)hipFuncSetAttribute((const void*)gemm256_kernel<0, 1>,
                              hipFuncAttributeMaxDynamicSharedMemorySize, 131072);

    cvt_kernel<<<(NTOK * D_MODEL / 8) / 256, 256, 0, stream>>>(x, xbf);
    dim3 gt1(QKV_N / 64, D_MODEL / 64);
    transpose_kernel<<<gt1, 256, 0, stream>>>(W_attn, WT, D_MODEL, QKV_N);
    dim3 gt2(D_MODEL / 64, D_MODEL / 64);
    transpose_kernel<<<gt2, 256, 0, stream>>>(W_proj, WpT, D_MODEL, D_MODEL);

    // qkv = x @ W_attn + b_attn  (+ fused V^T copy and f32 present k/v)
    dim3 g1(QKV_N / 256, NTOK / 256);   // 12 x 32 = 384 blocks
    gemm256_kernel<0, 1><<<g1, 512, 131072, stream>>>(xbf, WT, b_attn, qkv,
                                                      vtg, pres,
                                                      NTOK, QKV_N, D_MODEL);

    // causal attention (wave-paired q-tiles, counted-vmcnt pipeline)
    attn_kernel<<<512, 512, 0, stream>>>(qkv, vtg, aout);

    // out = aout @ W_proj + b_proj
    dim3 g2(D_MODEL / 128, NTOK / 128);
    gemm_bt_kernel<1><<<g2, 256, 0, stream>>>(aout, WpT, b_proj, out,
                                              NTOK, D_MODEL, D_MODEL);
}

// Round 16
// 196.140 us; speedup vs baseline: 1.0372x; 1.0372x over previous
//
#include <hip/hip_runtime.h>

typedef __attribute__((ext_vector_type(8))) short short8;
typedef __attribute__((ext_vector_type(4))) short short4v;
typedef __attribute__((ext_vector_type(4))) float f32x4;
typedef __attribute__((ext_vector_type(16))) float f32x16;
typedef __attribute__((ext_vector_type(4))) unsigned int u32x4;
typedef __attribute__((ext_vector_type(2))) unsigned int u32x2;
typedef unsigned int u32;

#define D_MODEL 1024
#define HEADS 16
#define KD 64
#define SEQ 2048
#define BATCH 4
#define NTOK (BATCH*SEQ)    /* 8192 */
#define QKV_N (3*D_MODEL)   /* 3072 */

#define WAIT_VM(n) asm volatile("s_waitcnt vmcnt(" #n ")" ::: "memory")

__device__ inline float bf2f(unsigned short u) {
    unsigned x = ((unsigned)u) << 16;
    return __builtin_bit_cast(float, x);
}
__device__ inline unsigned short f2bf(float f) {
    unsigned u = __builtin_bit_cast(unsigned, f);
    u += 0x7FFFu + ((u >> 16) & 1u);
    return (unsigned short)(u >> 16);
}
__device__ __forceinline__ void gload_lds16(const unsigned short* g, unsigned short* l) {
    __builtin_amdgcn_global_load_lds(
        (const __attribute__((address_space(1))) void*)g,
        (__attribute__((address_space(3))) void*)l, 16, 0, 0);
}
__device__ __forceinline__ u32 cvtpk(float lo, float hi) {
    u32 r; asm("v_cvt_pk_bf16_f32 %0, %1, %2" : "=v"(r) : "v"(lo), "v"(hi)); return r;
}
__device__ __forceinline__ void pl32swap(u32& a, u32& b) {
#if __has_builtin(__builtin_amdgcn_permlane32_swap)
    u32x2 r = __builtin_amdgcn_permlane32_swap(a, b, 0, 0);
    a = r[0]; b = r[1];
#else
    u32 pa = (u32)__shfl_xor((int)a, 32, 64);
    u32 pb = (u32)__shfl_xor((int)b, 32, 64);
    bool hb = (threadIdx.x & 32) != 0;
    u32 na = hb ? pb : a;
    u32 nb = hb ? b : pa;
    a = na; b = nb;
#endif
}
__device__ __forceinline__ float pairmax(float x) {
    u32 a = __builtin_bit_cast(u32, x), b = a;
    pl32swap(a, b);
    return fmaxf(x, fmaxf(__builtin_bit_cast(float, a), __builtin_bit_cast(float, b)));
}
__device__ __forceinline__ float pairsum(float x) {
    u32 a = __builtin_bit_cast(u32, x), b = a;
    pl32swap(a, b);
    return __builtin_bit_cast(float, a) + __builtin_bit_cast(float, b);
}

// ---------------------------------------------------------------------------
// Merged prep: blocks [0,4096): x f32->bf16 (8 elems/thread);
// [4096,4864): transpose W_attn -> WT; [4864,5120): transpose W_proj -> WpT.
// ---------------------------------------------------------------------------
__global__ __launch_bounds__(256) void prep_kernel(
    const float* __restrict__ x, unsigned short* __restrict__ xbf,
    const float* __restrict__ Wa, unsigned short* __restrict__ WT,
    const float* __restrict__ Wp, unsigned short* __restrict__ WpT)
{
    __shared__ unsigned short T[64][80];
    const int tid = threadIdx.x;
    const int bid = blockIdx.x;

    if (bid < 4096) {
        size_t i = (size_t)bid * 256 + tid;
        f32x4 a = *reinterpret_cast<const f32x4*>(x + i*8);
        f32x4 b = *reinterpret_cast<const f32x4*>(x + i*8 + 4);
        short8 o;
        #pragma unroll
        for (int j = 0; j < 4; ++j) { o[j] = (short)f2bf(a[j]); o[j+4] = (short)f2bf(b[j]); }
        *reinterpret_cast<short8*>(xbf + i*8) = o;
        return;
    }

    const float* W; unsigned short* WTo; int K, N, n0, k0;
    if (bid < 4096 + 768) {
        int t = bid - 4096;
        W = Wa; WTo = WT; K = D_MODEL; N = QKV_N;
        n0 = (t % 48) * 64; k0 = (t / 48) * 64;
    } else {
        int t = bid - 4096 - 768;
        W = Wp; WTo = WpT; K = D_MODEL; N = D_MODEL;
        n0 = (t % 16) * 64; k0 = (t / 16) * 64;
    }

    int r  = tid >> 2;
    int cq = tid & 3;
    const float* src = W + (size_t)(k0 + r) * N + n0 + cq*16;
    #pragma unroll
    for (int q = 0; q < 4; ++q) {
        f32x4 v = *reinterpret_cast<const f32x4*>(src + q*4);
        #pragma unroll
        for (int j = 0; j < 4; ++j) T[cq*16 + q*4 + j][r] = f2bf(v[j]);
    }
    __syncthreads();
    int c  = tid >> 2;
    int rq = tid & 3;
    short8 o0 = *reinterpret_cast<const short8*>(&T[c][rq*16]);
    short8 o1 = *reinterpret_cast<const short8*>(&T[c][rq*16 + 8]);
    unsigned short* dst = WTo + (size_t)(n0 + c) * K + k0 + rq*16;
    *reinterpret_cast<short8*>(dst)     = o0;
    *reinterpret_cast<short8*>(dst + 8) = o1;
}

// ---------------------------------------------------------------------------
// Y = A[M,K](bf16) @ BT[N,K]^T(bf16) + bias(f32).  128x128 tile, BK=64,
// 4 waves (2x2), 2-deep pipelined global_load_lds with COUNTED vmcnt,
// raw s_barrier, pre-swizzled source + swizzled ds_read. XCD block swizzle.
// FUSE: write vtg (bf16 V^T) + f32 present k/v; SKIP dead qkv V-third write.
// ---------------------------------------------------------------------------
template<int Y_F32, int FUSE>
__global__ __launch_bounds__(256) void gemm_bt_kernel(
    const unsigned short* __restrict__ A, const unsigned short* __restrict__ BT,
    const float* __restrict__ bias, void* __restrict__ Yv,
    unsigned short* __restrict__ vtg, float* __restrict__ pres,
    int M, int N, int K)
{
    __shared__ unsigned short sA[2][128*64];
    __shared__ unsigned short sB[2][128*64];

    const int tid = threadIdx.x, lane = tid & 63, w = tid >> 6;
    const int l15 = lane & 15, lg = lane >> 4;

    const int nwg = gridDim.x * gridDim.y;
    const int bid = blockIdx.y * gridDim.x + blockIdx.x;
    const int swz = (bid & 7) * (nwg >> 3) + (bid >> 3);
    const int n0 = (swz % gridDim.x) * 128;
    const int m0 = (swz / gridDim.x) * 128;

    const int wr = w >> 1, wc = w & 1;

    f32x4 acc[4][4];
    #pragma unroll
    for (int m = 0; m < 4; ++m)
        #pragma unroll
        for (int n = 0; n < 4; ++n) acc[m][n] = f32x4{0,0,0,0};

    const int ldrow = (lane >> 3);
    const int slot  = lane & 7;
    const int nkt = K >> 6;

    // prologue: stage k-tiles 0 and 1
    #pragma unroll
    for (int i = 0; i < 4; ++i) {
        int kb  = w*4 + i;
        int row = kb*8 + ldrow;
        int sc  = slot ^ (row & 7);
        gload_lds16(&A [(size_t)(m0 + row) * K + sc*8], &sA[0][kb*512]);
        gload_lds16(&BT[(size_t)(n0 + row) * K + sc*8], &sB[0][kb*512]);
    }
    #pragma unroll
    for (int i = 0; i < 4; ++i) {
        int kb  = w*4 + i;
        int row = kb*8 + ldrow;
        int sc  = slot ^ (row & 7);
        gload_lds16(&A [(size_t)(m0 + row) * K + 64 + sc*8], &sA[1][kb*512]);
        gload_lds16(&BT[(size_t)(n0 + row) * K + 64 + sc*8], &sB[1][kb*512]);
    }

    for (int kt = 0; kt < nkt; ++kt) {
        const int buf = kt & 1;

        if (kt == nkt - 1) { WAIT_VM(0); } else { WAIT_VM(8); }
        __builtin_amdgcn_sched_barrier(0);
        __builtin_amdgcn_s_barrier();

        #pragma unroll
        for (int kk = 0; kk < 2; ++kk) {
            short8 af[4], bfr[4];
            #pragma unroll
            for (int m = 0; m < 4; ++m) {
                int row = wr*64 + m*16 + l15;
                int ch  = (4*kk + lg) ^ (row & 7);
                af[m] = *reinterpret_cast<const short8*>(&sA[buf][row*64 + ch*8]);
            }
            #pragma unroll
            for (int n = 0; n < 4; ++n) {
                int row = wc*64 + n*16 + l15;
                int ch  = (4*kk + lg) ^ (row & 7);
                bfr[n] = *reinterpret_cast<const short8*>(&sB[buf][row*64 + ch*8]);
            }
            __builtin_amdgcn_s_setprio(1);
            #pragma unroll
            for (int m = 0; m < 4; ++m)
                #pragma unroll
                for (int n = 0; n < 4; ++n)
                    acc[m][n] = __builtin_amdgcn_mfma_f32_16x16x32_bf16(
                        af[m], bfr[n], acc[m][n], 0, 0, 0);
            __builtin_amdgcn_s_setprio(0);
        }

        __builtin_amdgcn_s_barrier();
        __builtin_amdgcn_sched_barrier(0);
        if (kt + 2 < nkt) {
            const int k2 = (kt + 2) << 6;
            #pragma unroll
            for (int i = 0; i < 4; ++i) {
                int kb  = w*4 + i;
                int row = kb*8 + ldrow;
                int sc  = slot ^ (row & 7);
                gload_lds16(&A [(size_t)(m0 + row) * K + k2 + sc*8], &sA[buf][kb*512]);
                gload_lds16(&BT[(size_t)(n0 + row) * K + k2 + sc*8], &sB[buf][kb*512]);
            }
        }
    }

    const bool vThird = FUSE && (n0 < D_MODEL);       // qkv V-cols: dead, skip Y
    #pragma unroll
    for (int n = 0; n < 4; ++n) {
        int col = n0 + wc*64 + n*16 + l15;
        float bv = bias[col];
        #pragma unroll
        for (int m = 0; m < 4; ++m) {
            int row0 = m0 + wr*64 + m*16 + lg*4;
            float v0 = acc[m][n][0] + bv;
            float v1 = acc[m][n][1] + bv;
            float v2 = acc[m][n][2] + bv;
            float v3 = acc[m][n][3] + bv;
            if (!vThird) {
                if (Y_F32) {
                    float* Y = (float*)Yv;
                    Y[(size_t)(row0+0) * N + col] = v0;
                    Y[(size_t)(row0+1) * N + col] = v1;
                    Y[(size_t)(row0+2) * N + col] = v2;
                    Y[(size_t)(row0+3) * N + col] = v3;
                } else {
                    unsigned short* Y = (unsigned short*)Yv;
                    Y[(size_t)(row0+0) * N + col] = f2bf(v0);
                    Y[(size_t)(row0+1) * N + col] = f2bf(v1);
                    Y[(size_t)(row0+2) * N + col] = f2bf(v2);
                    Y[(size_t)(row0+3) * N + col] = f2bf(v3);
                }
            }
            if (FUSE && n0 < D_MODEL) {   // V cols: vtg (bf16 V^T) + f32 present[1]
                int hh = col >> 6, dd = col & 63;
                int bb = row0 >> 11, ss = row0 & (SEQ - 1);
                short4v pk;
                pk[0] = (short)f2bf(v0); pk[1] = (short)f2bf(v1);
                pk[2] = (short)f2bf(v2); pk[3] = (short)f2bf(v3);
                *reinterpret_cast<short4v*>(
                    vtg + (((size_t)bb*HEADS + hh)*KD + dd)*SEQ + ss) = pk;
                float* pv = pres + (size_t)BATCH*HEADS*SEQ*KD
                          + (((size_t)bb*HEADS + hh)*SEQ + ss)*KD + dd;
                pv[0] = v0; pv[KD] = v1; pv[2*KD] = v2; pv[3*KD] = v3;
            }
            if (FUSE && n0 >= 2*D_MODEL) {  // K cols: f32 present[0]
                int rel = col - 2*D_MODEL;
                int hh = rel >> 6, dd = rel & 63;
                int bb = row0 >> 11, ss = row0 & (SEQ - 1);
                float* pk2 = pres + (((size_t)bb*HEADS + hh)*SEQ + ss)*KD + dd;
                pk2[0] = v0; pk2[KD] = v1; pk2[2*KD] = v2; pk2[3*KD] = v3;
            }
        }
    }
}

// ---------------------------------------------------------------------------
// Flash attention (r14 proven): swapped-operand 32x32 MFMA, wave-paired
// q-tiles, shared K/V staging, 2-deep counted-vmcnt pipeline.
// ---------------------------------------------------------------------------
__global__ __launch_bounds__(512) void attn_kernel(
    const unsigned short* __restrict__ qkv,
    const unsigned short* __restrict__ vtg,
    unsigned short* __restrict__ aout)
{
    __shared__ unsigned short Kl[2][64*64];
    __shared__ unsigned short Vl[2][64*64];

    const int tid  = threadIdx.x;
    const int lane = tid & 63;
    const int w    = tid >> 6;
    const int wg   = w >> 2;
    const int wl   = w & 3;
    const int l31  = lane & 31, hi = lane >> 5;

    const int bid = blockIdx.x;
    const int hb  = bid & 63;
    const int i   = 7 - (bid >> 6);
    const int qb  = 2*i + wg;
    const int h = hb & 15, b = hb >> 4;

    const unsigned short* base  = qkv + (size_t)b * SEQ * QKV_N;
    const unsigned short* vbase = vtg + ((size_t)b * HEADS + h) * KD * SEQ;
    const int qoff = D_MODEL + h*KD;
    const int koff = 2*D_MODEL + h*KD;

    const float SCALE2 = 0.125f * 1.44269504088896f;
    const float THR_RAW = 44.36f;

    const int ldrow = lane >> 3;
    const int slot  = lane & 7;
    const int ksw   = l31 & 7;

    const int q0 = qb * 128;
    const int qrow  = q0 + wl*32 + l31;
    const int qminw = q0 + wl*32;

    short8 qf[4];
    #pragma unroll
    for (int ks = 0; ks < 4; ++ks)
        qf[ks] = *reinterpret_cast<const short8*>(
            base + (size_t)qrow * QKV_N + qoff + ks*16 + hi*8);

    f32x16 o0, o1;
    #pragma unroll
    for (int r = 0; r < 16; ++r) { o0[r] = 0.f; o1[r] = 0.f; }
    float m = -1e30f, msc = -1e30f * 0.180336887f, sr = 0.f;

    const int nt = 4*i + 4;

    {
        int row = w*8 + ldrow, sc = slot ^ (row & 7);
        gload_lds16(&base[(size_t)row * QKV_N + koff + sc*8], &Kl[0][w*512]);
        gload_lds16(&vbase[(size_t)row * SEQ + sc*8],         &Vl[0][w*512]);
        gload_lds16(&base[(size_t)(64 + row) * QKV_N + koff + sc*8], &Kl[1][w*512]);
        gload_lds16(&vbase[(size_t)row * SEQ + 64 + sc*8],           &Vl[1][w*512]);
    }

    for (int t = 0; t < nt; ++t) {
        const int buf = t & 1;

        if (t == nt - 1) { WAIT_VM(0); } else { WAIT_VM(2); }
        __builtin_amdgcn_sched_barrier(0);
        __builtin_amdgcn_s_barrier();

        const int d0 = qminw - t*64;
        if (d0 > -32) {
            f32x16 sa, sb;
            #pragma unroll
            for (int r = 0; r < 16; ++r) { sa[r] = 0.f; sb[r] = 0.f; }
            __builtin_amdgcn_s_setprio(1);
            #pragma unroll
            for (int ks = 0; ks < 4; ++ks) {
                short8 kf = *reinterpret_cast<const short8*>(
                    &Kl[buf][l31*64 + ((2*ks + hi) ^ ksw)*8]);
                sa = __builtin_amdgcn_mfma_f32_32x32x16_bf16(kf, qf[ks], sa, 0, 0, 0);
            }
            #pragma unroll
            for (int ks = 0; ks < 4; ++ks) {
                short8 kf = *reinterpret_cast<const short8*>(
                    &Kl[buf][(32 + l31)*64 + ((2*ks + hi) ^ ksw)*8]);
                sb = __builtin_amdgcn_mfma_f32_32x32x16_bf16(kf, qf[ks], sb, 0, 0, 0);
            }
            __builtin_amdgcn_s_setprio(0);

            if (d0 <= 32) {
                const int kqA = l31 + d0      - 4*hi;
                const int kqB = l31 + d0 - 32 - 4*hi;
                #pragma unroll
                for (int r = 0; r < 16; ++r) {
                    const int cr = (r & 3) + 8*(r >> 2);
                    if (d0 == 0) sa[r] = (cr <= kqA) ? sa[r] : -1e30f;
                    sb[r] = (cr <= kqB) ? sb[r] : -1e30f;
                }
            }

            float x[8];
            #pragma unroll
            for (int ii = 0; ii < 8; ++ii)
                x[ii] = fmaxf(fmaxf(sa[2*ii], sa[2*ii+1]), fmaxf(sb[2*ii], sb[2*ii+1]));
            float pm = fmaxf(fmaxf(fmaxf(x[0], x[1]), fmaxf(x[2], x[3])),
                             fmaxf(fmaxf(x[4], x[5]), fmaxf(x[6], x[7])));
            pm = pairmax(pm);
            if (!__all(pm <= m + THR_RAW)) {
                float mn  = fmaxf(m, pm);
                float fac = exp2f((m - mn) * SCALE2);
                sr *= fac;
                #pragma unroll
                for (int r = 0; r < 16; ++r) { o0[r] *= fac; o1[r] *= fac; }
                m = mn; msc = m * SCALE2;
            }

            #pragma unroll
            for (int r = 0; r < 16; ++r) {
                sa[r] = exp2f(sa[r]*SCALE2 - msc);
                sb[r] = exp2f(sb[r]*SCALE2 - msc);
            }
            float u[8];
            #pragma unroll
            for (int ii = 0; ii < 8; ++ii)
                u[ii] = (sa[2*ii] + sa[2*ii+1]) + (sb[2*ii] + sb[2*ii+1]);
            float ts = ((u[0]+u[1]) + (u[2]+u[3])) + ((u[4]+u[5]) + (u[6]+u[7]));
            sr += pairsum(ts);

            u32 WA[8], WB[8];
            #pragma unroll
            for (int wi = 0; wi < 8; ++wi) {
                WA[wi] = cvtpk(sa[2*wi], sa[2*wi+1]);
                WB[wi] = cvtpk(sb[2*wi], sb[2*wi+1]);
            }

            #pragma unroll
            for (int h32 = 0; h32 < 2; ++h32) {
                #pragma unroll
                for (int ks = 0; ks < 2; ++ks) {
                    u32 W0 = h32 ? WB[4*ks+0] : WA[4*ks+0];
                    u32 W1 = h32 ? WB[4*ks+1] : WA[4*ks+1];
                    u32 W2 = h32 ? WB[4*ks+2] : WA[4*ks+2];
                    u32 W3 = h32 ? WB[4*ks+3] : WA[4*ks+3];
                    u32 s0 = hi ? W0 : W2;
                    u32 s1 = hi ? W1 : W3;
                    u32 r0 = (u32)__shfl_xor((int)s0, 32, 64);
                    u32 r1 = (u32)__shfl_xor((int)s1, 32, 64);
                    u32x4 wv;
                    wv[0] = hi ? r0 : W0;
                    wv[1] = hi ? r1 : W1;
                    wv[2] = hi ? W2 : r0;
                    wv[3] = hi ? W3 : r1;
                    short8 pfrag = __builtin_bit_cast(short8, wv);
                    __builtin_amdgcn_s_setprio(1);
                    #pragma unroll
                    for (int dt = 0; dt < 2; ++dt) {
                        short8 vf = *reinterpret_cast<const short8*>(
                            &Vl[buf][(dt*32 + l31)*64 + ((4*h32 + 2*ks + hi) ^ ksw)*8]);
                        if (dt == 0)
                            o0 = __builtin_amdgcn_mfma_f32_32x32x16_bf16(vf, pfrag, o0, 0, 0, 0);
                        else
                            o1 = __builtin_amdgcn_mfma_f32_32x32x16_bf16(vf, pfrag, o1, 0, 0, 0);
                    }
                    __builtin_amdgcn_s_setprio(0);
                }
            }
        }

        __builtin_amdgcn_s_barrier();
        __builtin_amdgcn_sched_barrier(0);
        if (t + 2 < nt) {
            int row = w*8 + ldrow, sc = slot ^ (row & 7);
            gload_lds16(&base[(size_t)((t+2)*64 + row) * QKV_N + koff + sc*8],
                        &Kl[buf][w*512]);
            gload_lds16(&vbase[(size_t)row * SEQ + (t+2)*64 + sc*8],
                        &Vl[buf][w*512]);
        }
    }

    const float inv = 1.0f / sr;
    unsigned short* orow = aout + ((size_t)b * SEQ + qrow) * D_MODEL + h*KD;
    #pragma unroll
    for (int dt = 0; dt < 2; ++dt) {
        #pragma unroll
        for (int g = 0; g < 4; ++g) {
            short4v pk;
            #pragma unroll
            for (int j = 0; j < 4; ++j) {
                float v = (dt == 0 ? o0[4*g + j] : o1[4*g + j]) * inv;
                pk[j] = (short)f2bf(v);
            }
            *reinterpret_cast<short4v*>(orow + dt*32 + 8*g + 4*hi) = pk;
        }
    }
}

// ---------------------------------------------------------------------------
extern "C" void kernel_launch(void* const* d_in, const int* in_sizes, int n_in,
                              void* d_out, int out_size, void* d_ws, size_t ws_size,
                              hipStream_t stream)
{
    const float* x      = (const float*)d_in[0];
    const float* W_attn = (const float*)d_in[1];
    const float* b_attn = (const float*)d_in[2];
    const float* W_proj = (const float*)d_in[3];
    const float* b_proj = (const float*)d_in[4];
    float* out = (float*)d_out;

    unsigned short* qkv  = (unsigned short*)d_ws;                  // [8192][3072]
    unsigned short* xbf  = qkv + (size_t)NTOK * QKV_N;             // [8192][1024] (= aout later)
    unsigned short* aout = xbf;
    unsigned short* WT   = xbf + (size_t)NTOK * D_MODEL;           // [3072][1024]
    unsigned short* WpT  = WT + (size_t)QKV_N * D_MODEL;           // [1024][1024]
    unsigned short* vtg  = WpT + (size_t)D_MODEL * D_MODEL;        // [4][16][64][2048]
    float* pres = out + (size_t)NTOK * D_MODEL;                    // [2,4,16,2048,64] f32

    // merged prep: cvt + both weight transposes (independent, one launch)
    prep_kernel<<<4096 + 768 + 256, 256, 0, stream>>>(x, xbf, W_attn, WT,
                                                      W_proj, WpT);

    // qkv = x @ W_attn + b_attn  (+ fused V^T copy and f32 present k/v)
    dim3 g1(QKV_N / 128, NTOK / 128);
    gemm_bt_kernel<0, 1><<<g1, 256, 0, stream>>>(xbf, WT, b_attn, qkv, vtg, pres,
                                                 NTOK, QKV_N, D_MODEL);

    // causal attention (wave-paired q-tiles, counted-vmcnt pipeline)
    attn_kernel<<<512, 512, 0, stream>>>(qkv, vtg, aout);

    // out = aout @ W_proj + b_proj
    dim3 g2(D_MODEL / 128, NTOK / 128);
    gemm_bt_kernel<1, 0><<<g2, 256, 0, stream>>>(aout, WpT, b_proj, out,
                                                 nullptr, nullptr,
                                                 NTOK, D_MODEL, D_MODEL);
}

// Round 18
// 189.572 us; speedup vs baseline: 1.0732x; 1.0346x over previous
//
#include <hip/hip_runtime.h>

typedef __attribute__((ext_vector_type(8))) short short8;
typedef __attribute__((ext_vector_type(4))) short short4v;
typedef __attribute__((ext_vector_type(4))) float f32x4;
typedef __attribute__((ext_vector_type(16))) float f32x16;
typedef __attribute__((ext_vector_type(4))) unsigned int u32x4;
typedef __attribute__((ext_vector_type(2))) unsigned int u32x2;
typedef unsigned int u32;

#define D_MODEL 1024
#define HEADS 16
#define KD 64
#define SEQ 2048
#define BATCH 4
#define NTOK (BATCH*SEQ)    /* 8192 */
#define QKV_N (3*D_MODEL)   /* 3072 */

#define WAIT_VM(n) asm volatile("s_waitcnt vmcnt(" #n ")" ::: "memory")

__device__ inline float bf2f(unsigned short u) {
    unsigned x = ((unsigned)u) << 16;
    return __builtin_bit_cast(float, x);
}
__device__ inline unsigned short f2bf(float f) {
    unsigned u = __builtin_bit_cast(unsigned, f);
    u += 0x7FFFu + ((u >> 16) & 1u);
    return (unsigned short)(u >> 16);
}
__device__ __forceinline__ void gload_lds16(const unsigned short* g, unsigned short* l) {
    __builtin_amdgcn_global_load_lds(
        (const __attribute__((address_space(1))) void*)g,
        (__attribute__((address_space(3))) void*)l, 16, 0, 0);
}
__device__ __forceinline__ u32 cvtpk(float lo, float hi) {
    u32 r; asm("v_cvt_pk_bf16_f32 %0, %1, %2" : "=v"(r) : "v"(lo), "v"(hi)); return r;
}
__device__ __forceinline__ void pl32swap(u32& a, u32& b) {
#if __has_builtin(__builtin_amdgcn_permlane32_swap)
    u32x2 r = __builtin_amdgcn_permlane32_swap(a, b, 0, 0);
    a = r[0]; b = r[1];
#else
    u32 pa = (u32)__shfl_xor((int)a, 32, 64);
    u32 pb = (u32)__shfl_xor((int)b, 32, 64);
    bool hb = (threadIdx.x & 32) != 0;
    u32 na = hb ? pb : a;
    u32 nb = hb ? b : pa;
    a = na; b = nb;
#endif
}
__device__ __forceinline__ float pairmax(float x) {
    u32 a = __builtin_bit_cast(u32, x), b = a;
    pl32swap(a, b);
    return fmaxf(x, fmaxf(__builtin_bit_cast(float, a), __builtin_bit_cast(float, b)));
}
__device__ __forceinline__ float pairsum(float x) {
    u32 a = __builtin_bit_cast(u32, x), b = a;
    pl32swap(a, b);
    return __builtin_bit_cast(float, a) + __builtin_bit_cast(float, b);
}

// ---------------------------------------------------------------------------
// Merged prep: blocks [0,4096): x f32->bf16 (8 elems/thread);
// [4096,4864): transpose W_attn -> WT; [4864,5120): transpose W_proj -> WpT.
// ---------------------------------------------------------------------------
__global__ __launch_bounds__(256) void prep_kernel(
    const float* __restrict__ x, unsigned short* __restrict__ xbf,
    const float* __restrict__ Wa, unsigned short* __restrict__ WT,
    const float* __restrict__ Wp, unsigned short* __restrict__ WpT)
{
    __shared__ unsigned short T[64][80];
    const int tid = threadIdx.x;
    const int bid = blockIdx.x;

    if (bid < 4096) {
        size_t i = (size_t)bid * 256 + tid;
        f32x4 a = *reinterpret_cast<const f32x4*>(x + i*8);
        f32x4 b = *reinterpret_cast<const f32x4*>(x + i*8 + 4);
        short8 o;
        #pragma unroll
        for (int j = 0; j < 4; ++j) { o[j] = (short)f2bf(a[j]); o[j+4] = (short)f2bf(b[j]); }
        *reinterpret_cast<short8*>(xbf + i*8) = o;
        return;
    }

    const float* W; unsigned short* WTo; int K, N, n0, k0;
    if (bid < 4096 + 768) {
        int t = bid - 4096;
        W = Wa; WTo = WT; K = D_MODEL; N = QKV_N;
        n0 = (t % 48) * 64; k0 = (t / 48) * 64;
    } else {
        int t = bid - 4096 - 768;
        W = Wp; WTo = WpT; K = D_MODEL; N = D_MODEL;
        n0 = (t % 16) * 64; k0 = (t / 16) * 64;
    }

    int r  = tid >> 2;
    int cq = tid & 3;
    const float* src = W + (size_t)(k0 + r) * N + n0 + cq*16;
    #pragma unroll
    for (int q = 0; q < 4; ++q) {
        f32x4 v = *reinterpret_cast<const f32x4*>(src + q*4);
        #pragma unroll
        for (int j = 0; j < 4; ++j) T[cq*16 + q*4 + j][r] = f2bf(v[j]);
    }
    __syncthreads();
    int c  = tid >> 2;
    int rq = tid & 3;
    short8 o0 = *reinterpret_cast<const short8*>(&T[c][rq*16]);
    short8 o1 = *reinterpret_cast<const short8*>(&T[c][rq*16 + 8]);
    unsigned short* dst = WTo + (size_t)(n0 + c) * K + k0 + rq*16;
    *reinterpret_cast<short8*>(dst)     = o0;
    *reinterpret_cast<short8*>(dst + 8) = o1;
}

// ---------------------------------------------------------------------------
// Y = A[M,K](bf16) @ BT[N,K]^T(bf16) + bias(f32).  128x128 tile, BK=64,
// 4 waves (2x2), 2-deep pipelined global_load_lds with COUNTED vmcnt,
// raw s_barrier, pre-swizzled source + swizzled ds_read. XCD block swizzle.
// FUSE: write vtg (bf16 V^T) + f32 present k/v; SKIP dead qkv V-third write.
// ---------------------------------------------------------------------------
template<int Y_F32, int FUSE>
__global__ __launch_bounds__(256) void gemm_bt_kernel(
    const unsigned short* __restrict__ A, const unsigned short* __restrict__ BT,
    const float* __restrict__ bias, void* __restrict__ Yv,
    unsigned short* __restrict__ vtg, float* __restrict__ pres,
    int M, int N, int K)
{
    __shared__ unsigned short sA[2][128*64];
    __shared__ unsigned short sB[2][128*64];

    const int tid = threadIdx.x, lane = tid & 63, w = tid >> 6;
    const int l15 = lane & 15, lg = lane >> 4;

    const int nwg = gridDim.x * gridDim.y;
    const int bid = blockIdx.y * gridDim.x + blockIdx.x;
    const int swz = (bid & 7) * (nwg >> 3) + (bid >> 3);
    const int n0 = (swz % gridDim.x) * 128;
    const int m0 = (swz / gridDim.x) * 128;

    const int wr = w >> 1, wc = w & 1;

    f32x4 acc[4][4];
    #pragma unroll
    for (int m = 0; m < 4; ++m)
        #pragma unroll
        for (int n = 0; n < 4; ++n) acc[m][n] = f32x4{0,0,0,0};

    const int ldrow = (lane >> 3);
    const int slot  = lane & 7;
    const int nkt = K >> 6;

    // prologue: stage k-tiles 0 and 1
    #pragma unroll
    for (int i = 0; i < 4; ++i) {
        int kb  = w*4 + i;
        int row = kb*8 + ldrow;
        int sc  = slot ^ (row & 7);
        gload_lds16(&A [(size_t)(m0 + row) * K + sc*8], &sA[0][kb*512]);
        gload_lds16(&BT[(size_t)(n0 + row) * K + sc*8], &sB[0][kb*512]);
    }
    #pragma unroll
    for (int i = 0; i < 4; ++i) {
        int kb  = w*4 + i;
        int row = kb*8 + ldrow;
        int sc  = slot ^ (row & 7);
        gload_lds16(&A [(size_t)(m0 + row) * K + 64 + sc*8], &sA[1][kb*512]);
        gload_lds16(&BT[(size_t)(n0 + row) * K + 64 + sc*8], &sB[1][kb*512]);
    }

    for (int kt = 0; kt < nkt; ++kt) {
        const int buf = kt & 1;

        if (kt == nkt - 1) { WAIT_VM(0); } else { WAIT_VM(8); }
        __builtin_amdgcn_sched_barrier(0);
        __builtin_amdgcn_s_barrier();

        #pragma unroll
        for (int kk = 0; kk < 2; ++kk) {
            short8 af[4], bfr[4];
            #pragma unroll
            for (int m = 0; m < 4; ++m) {
                int row = wr*64 + m*16 + l15;
                int ch  = (4*kk + lg) ^ (row & 7);
                af[m] = *reinterpret_cast<const short8*>(&sA[buf][row*64 + ch*8]);
            }
            #pragma unroll
            for (int n = 0; n < 4; ++n) {
                int row = wc*64 + n*16 + l15;
                int ch  = (4*kk + lg) ^ (row & 7);
                bfr[n] = *reinterpret_cast<const short8*>(&sB[buf][row*64 + ch*8]);
            }
            __builtin_amdgcn_s_setprio(1);
            #pragma unroll
            for (int m = 0; m < 4; ++m)
                #pragma unroll
                for (int n = 0; n < 4; ++n)
                    acc[m][n] = __builtin_amdgcn_mfma_f32_16x16x32_bf16(
                        af[m], bfr[n], acc[m][n], 0, 0, 0);
            __builtin_amdgcn_s_setprio(0);
        }

        __builtin_amdgcn_s_barrier();
        __builtin_amdgcn_sched_barrier(0);
        if (kt + 2 < nkt) {
            const int k2 = (kt + 2) << 6;
            #pragma unroll
            for (int i = 0; i < 4; ++i) {
                int kb  = w*4 + i;
                int row = kb*8 + ldrow;
                int sc  = slot ^ (row & 7);
                gload_lds16(&A [(size_t)(m0 + row) * K + k2 + sc*8], &sA[buf][kb*512]);
                gload_lds16(&BT[(size_t)(n0 + row) * K + k2 + sc*8], &sB[buf][kb*512]);
            }
        }
    }

    const bool vThird = FUSE && (n0 < D_MODEL);       // qkv V-cols: dead, skip Y
    #pragma unroll
    for (int n = 0; n < 4; ++n) {
        int col = n0 + wc*64 + n*16 + l15;
        float bv = bias[col];
        #pragma unroll
        for (int m = 0; m < 4; ++m) {
            int row0 = m0 + wr*64 + m*16 + lg*4;
            float v0 = acc[m][n][0] + bv;
            float v1 = acc[m][n][1] + bv;
            float v2 = acc[m][n][2] + bv;
            float v3 = acc[m][n][3] + bv;
            if (!vThird) {
                if (Y_F32) {
                    float* Y = (float*)Yv;
                    Y[(size_t)(row0+0) * N + col] = v0;
                    Y[(size_t)(row0+1) * N + col] = v1;
                    Y[(size_t)(row0+2) * N + col] = v2;
                    Y[(size_t)(row0+3) * N + col] = v3;
                } else {
                    unsigned short* Y = (unsigned short*)Yv;
                    Y[(size_t)(row0+0) * N + col] = f2bf(v0);
                    Y[(size_t)(row0+1) * N + col] = f2bf(v1);
                    Y[(size_t)(row0+2) * N + col] = f2bf(v2);
                    Y[(size_t)(row0+3) * N + col] = f2bf(v3);
                }
            }
            if (FUSE && n0 < D_MODEL) {   // V cols: vtg (bf16 V^T) + f32 present[1]
                int hh = col >> 6, dd = col & 63;
                int bb = row0 >> 11, ss = row0 & (SEQ - 1);
                short4v pk;
                pk[0] = (short)f2bf(v0); pk[1] = (short)f2bf(v1);
                pk[2] = (short)f2bf(v2); pk[3] = (short)f2bf(v3);
                *reinterpret_cast<short4v*>(
                    vtg + (((size_t)bb*HEADS + hh)*KD + dd)*SEQ + ss) = pk;
                float* pv = pres + (size_t)BATCH*HEADS*SEQ*KD
                          + (((size_t)bb*HEADS + hh)*SEQ + ss)*KD + dd;
                pv[0] = v0; pv[KD] = v1; pv[2*KD] = v2; pv[3*KD] = v3;
            }
            if (FUSE && n0 >= 2*D_MODEL) {  // K cols: f32 present[0]
                int rel = col - 2*D_MODEL;
                int hh = rel >> 6, dd = rel & 63;
                int bb = row0 >> 11, ss = row0 & (SEQ - 1);
                float* pk2 = pres + (((size_t)bb*HEADS + hh)*SEQ + ss)*KD + dd;
                pk2[0] = v0; pk2[KD] = v1; pk2[2*KD] = v2; pk2[3*KD] = v3;
            }
        }
    }
}

// ---------------------------------------------------------------------------
// Flash attention (r14/r16 proven): swapped-operand 32x32 MFMA, wave-paired
// q-tiles, shared K/V staging, 2-deep counted-vmcnt pipeline.
// ---------------------------------------------------------------------------
__global__ __launch_bounds__(512) void attn_kernel(
    const unsigned short* __restrict__ qkv,
    const unsigned short* __restrict__ vtg,
    unsigned short* __restrict__ aout)
{
    __shared__ unsigned short Kl[2][64*64];
    __shared__ unsigned short Vl[2][64*64];

    const int tid  = threadIdx.x;
    const int lane = tid & 63;
    const int w    = tid >> 6;
    const int wg   = w >> 2;
    const int wl   = w & 3;
    const int l31  = lane & 31, hi = lane >> 5;

    const int bid = blockIdx.x;
    const int hb  = bid & 63;
    const int i   = 7 - (bid >> 6);
    const int qb  = 2*i + wg;
    const int h = hb & 15, b = hb >> 4;

    const unsigned short* base  = qkv + (size_t)b * SEQ * QKV_N;
    const unsigned short* vbase = vtg + ((size_t)b * HEADS + h) * KD * SEQ;
    const int qoff = D_MODEL + h*KD;
    const int koff = 2*D_MODEL + h*KD;

    const float SCALE2 = 0.125f * 1.44269504088896f;
    const float THR_RAW = 44.36f;

    const int ldrow = lane >> 3;
    const int slot  = lane & 7;
    const int ksw   = l31 & 7;

    const int q0 = qb * 128;
    const int qrow  = q0 + wl*32 + l31;
    const int qminw = q0 + wl*32;

    short8 qf[4];
    #pragma unroll
    for (int ks = 0; ks < 4; ++ks)
        qf[ks] = *reinterpret_cast<const short8*>(
            base + (size_t)qrow * QKV_N + qoff + ks*16 + hi*8);

    f32x16 o0, o1;
    #pragma unroll
    for (int r = 0; r < 16; ++r) { o0[r] = 0.f; o1[r] = 0.f; }
    float m = -1e30f, msc = -1e30f * 0.180336887f, sr = 0.f;

    const int nt = 4*i + 4;

    {
        int row = w*8 + ldrow, sc = slot ^ (row & 7);
        gload_lds16(&base[(size_t)row * QKV_N + koff + sc*8], &Kl[0][w*512]);
        gload_lds16(&vbase[(size_t)row * SEQ + sc*8],         &Vl[0][w*512]);
        gload_lds16(&base[(size_t)(64 + row) * QKV_N + koff + sc*8], &Kl[1][w*512]);
        gload_lds16(&vbase[(size_t)row * SEQ + 64 + sc*8],           &Vl[1][w*512]);
    }

    for (int t = 0; t < nt; ++t) {
        const int buf = t & 1;

        if (t == nt - 1) { WAIT_VM(0); } else { WAIT_VM(2); }
        __builtin_amdgcn_sched_barrier(0);
        __builtin_amdgcn_s_barrier();

        const int d0 = qminw - t*64;
        if (d0 > -32) {
            f32x16 sa, sb;
            #pragma unroll
            for (int r = 0; r < 16; ++r) { sa[r] = 0.f; sb[r] = 0.f; }
            __builtin_amdgcn_s_setprio(1);
            #pragma unroll
            for (int ks = 0; ks < 4; ++ks) {
                short8 kf = *reinterpret_cast<const short8*>(
                    &Kl[buf][l31*64 + ((2*ks + hi) ^ ksw)*8]);
                sa = __builtin_amdgcn_mfma_f32_32x32x16_bf16(kf, qf[ks], sa, 0, 0, 0);
            }
            #pragma unroll
            for (int ks = 0; ks < 4; ++ks) {
                short8 kf = *reinterpret_cast<const short8*>(
                    &Kl[buf][(32 + l31)*64 + ((2*ks + hi) ^ ksw)*8]);
                sb = __builtin_amdgcn_mfma_f32_32x32x16_bf16(kf, qf[ks], sb, 0, 0, 0);
            }
            __builtin_amdgcn_s_setprio(0);

            if (d0 <= 32) {
                const int kqA = l31 + d0      - 4*hi;
                const int kqB = l31 + d0 - 32 - 4*hi;
                #pragma unroll
                for (int r = 0; r < 16; ++r) {
                    const int cr = (r & 3) + 8*(r >> 2);
                    if (d0 == 0) sa[r] = (cr <= kqA) ? sa[r] : -1e30f;
                    sb[r] = (cr <= kqB) ? sb[r] : -1e30f;
                }
            }

            float x[8];
            #pragma unroll
            for (int ii = 0; ii < 8; ++ii)
                x[ii] = fmaxf(fmaxf(sa[2*ii], sa[2*ii+1]), fmaxf(sb[2*ii], sb[2*ii+1]));
            float pm = fmaxf(fmaxf(fmaxf(x[0], x[1]), fmaxf(x[2], x[3])),
                             fmaxf(fmaxf(x[4], x[5]), fmaxf(x[6], x[7])));
            pm = pairmax(pm);
            if (!__all(pm <= m + THR_RAW)) {
                float mn  = fmaxf(m, pm);
                float fac = exp2f((m - mn) * SCALE2);
                sr *= fac;
                #pragma unroll
                for (int r = 0; r < 16; ++r) { o0[r] *= fac; o1[r] *= fac; }
                m = mn; msc = m * SCALE2;
            }

            #pragma unroll
            for (int r = 0; r < 16; ++r) {
                sa[r] = exp2f(sa[r]*SCALE2 - msc);
                sb[r] = exp2f(sb[r]*SCALE2 - msc);
            }
            float u[8];
            #pragma unroll
            for (int ii = 0; ii < 8; ++ii)
                u[ii] = (sa[2*ii] + sa[2*ii+1]) + (sb[2*ii] + sb[2*ii+1]);
            float ts = ((u[0]+u[1]) + (u[2]+u[3])) + ((u[4]+u[5]) + (u[6]+u[7]));
            sr += pairsum(ts);

            u32 WA[8], WB[8];
            #pragma unroll
            for (int wi = 0; wi < 8; ++wi) {
                WA[wi] = cvtpk(sa[2*wi], sa[2*wi+1]);
                WB[wi] = cvtpk(sb[2*wi], sb[2*wi+1]);
            }

            #pragma unroll
            for (int h32 = 0; h32 < 2; ++h32) {
                #pragma unroll
                for (int ks = 0; ks < 2; ++ks) {
                    u32 W0 = h32 ? WB[4*ks+0] : WA[4*ks+0];
                    u32 W1 = h32 ? WB[4*ks+1] : WA[4*ks+1];
                    u32 W2 = h32 ? WB[4*ks+2] : WA[4*ks+2];
                    u32 W3 = h32 ? WB[4*ks+3] : WA[4*ks+3];
                    u32 s0 = hi ? W0 : W2;
                    u32 s1 = hi ? W1 : W3;
                    u32 r0 = (u32)__shfl_xor((int)s0, 32, 64);
                    u32 r1 = (u32)__shfl_xor((int)s1, 32, 64);
                    u32x4 wv;
                    wv[0] = hi ? r0 : W0;
                    wv[1] = hi ? r1 : W1;
                    wv[2] = hi ? W2 : r0;
                    wv[3] = hi ? W3 : r1;
                    short8 pfrag = __builtin_bit_cast(short8, wv);
                    __builtin_amdgcn_s_setprio(1);
                    #pragma unroll
                    for (int dt = 0; dt < 2; ++dt) {
                        short8 vf = *reinterpret_cast<const short8*>(
                            &Vl[buf][(dt*32 + l31)*64 + ((4*h32 + 2*ks + hi) ^ ksw)*8]);
                        if (dt == 0)
                            o0 = __builtin_amdgcn_mfma_f32_32x32x16_bf16(vf, pfrag, o0, 0, 0, 0);
                        else
                            o1 = __builtin_amdgcn_mfma_f32_32x32x16_bf16(vf, pfrag, o1, 0, 0, 0);
                    }
                    __builtin_amdgcn_s_setprio(0);
                }
            }
        }

        __builtin_amdgcn_s_barrier();
        __builtin_amdgcn_sched_barrier(0);
        if (t + 2 < nt) {
            int row = w*8 + ldrow, sc = slot ^ (row & 7);
            gload_lds16(&base[(size_t)((t+2)*64 + row) * QKV_N + koff + sc*8],
                        &Kl[buf][w*512]);
            gload_lds16(&vbase[(size_t)row * SEQ + (t+2)*64 + sc*8],
                        &Vl[buf][w*512]);
        }
    }

    const float inv = 1.0f / sr;
    unsigned short* orow = aout + ((size_t)b * SEQ + qrow) * D_MODEL + h*KD;
    #pragma unroll
    for (int dt = 0; dt < 2; ++dt) {
        #pragma unroll
        for (int g = 0; g < 4; ++g) {
            short4v pk;
            #pragma unroll
            for (int j = 0; j < 4; ++j) {
                float v = (dt == 0 ? o0[4*g + j] : o1[4*g + j]) * inv;
                pk[j] = (short)f2bf(v);
            }
            *reinterpret_cast<short4v*>(orow + dt*32 + 8*g + 4*hi) = pk;
        }
    }
}

// ---------------------------------------------------------------------------
extern "C" void kernel_launch(void* const* d_in, const int* in_sizes, int n_in,
                              void* d_out, int out_size, void* d_ws, size_t ws_size,
                              hipStream_t stream)
{
    const float* x      = (const float*)d_in[0];
    const float* W_attn = (const float*)d_in[1];
    const float* b_attn = (const float*)d_in[2];
    const float* W_proj = (const float*)d_in[3];
    const float* b_proj = (const float*)d_in[4];
    float* out = (float*)d_out;

    unsigned short* qkv  = (unsigned short*)d_ws;                  // [8192][3072]
    unsigned short* xbf  = qkv + (size_t)NTOK * QKV_N;             // [8192][1024] (= aout later)
    unsigned short* aout = xbf;
    unsigned short* WT   = xbf + (size_t)NTOK * D_MODEL;           // [3072][1024]
    unsigned short* WpT  = WT + (size_t)QKV_N * D_MODEL;           // [1024][1024]
    unsigned short* vtg  = WpT + (size_t)D_MODEL * D_MODEL;        // [4][16][64][2048]
    float* pres = out + (size_t)NTOK * D_MODEL;                    // [2,4,16,2048,64] f32

    // merged prep: cvt + both weight transposes (independent, one launch)
    prep_kernel<<<4096 + 768 + 256, 256, 0, stream>>>(x, xbf, W_attn, WT,
                                                      W_proj, WpT);

    // qkv = x @ W_attn + b_attn  (+ fused V^T copy and f32 present k/v)
    dim3 g1(QKV_N / 128, NTOK / 128);
    gemm_bt_kernel<0, 1><<<g1, 256, 0, stream>>>(xbf, WT, b_attn, qkv, vtg, pres,
                                                 NTOK, QKV_N, D_MODEL);

    // causal attention (wave-paired q-tiles, counted-vmcnt pipeline)
    attn_kernel<<<512, 512, 0, stream>>>(qkv, vtg, aout);

    // out = aout @ W_proj + b_proj
    dim3 g2(D_MODEL / 128, NTOK / 128);
    gemm_bt_kernel<1, 0><<<g2, 256, 0, stream>>>(aout, WpT, b_proj, out,
                                                 nullptr, nullptr,
                                                 NTOK, D_MODEL, D_MODEL);
}